// Round 1
// baseline (492.599 us; speedup 1.0000x reference)
//
#include <hip/hip_runtime.h>
#include <hip/hip_bf16.h>
#include <stdint.h>

// DequantingLinear: out[TOK,OUT] = x[TOK,IN] @ dequant(w_q,w_scales)^T + bias
// TOK=4096, IN=3072, OUT=12288, QK=32.
// Strategy: dequant W -> bf16 in ws, cvt x -> bf16 in ws, then m97-structure
// 128x128 bf16 MFMA GEMM (global_load_lds staging, XCD swizzle, bias epilogue).

typedef __bf16 bf16;
typedef __bf16 bf16x8 __attribute__((ext_vector_type(8)));
typedef float f32x4 __attribute__((ext_vector_type(4)));

#define AS1 __attribute__((address_space(1)))
#define AS3 __attribute__((address_space(3)))

__device__ __forceinline__ void gload_lds16(const void* g, void* l) {
    // 16B per lane, LDS dest = wave-uniform base + lane*16 (hardware rule)
    __builtin_amdgcn_global_load_lds((AS1 void*)g, (AS3 void*)l, 16, 0, 0);
}

// ---------------- Pass 1a: dequantize w_q (int32) * scale -> bf16 ----------
__global__ __launch_bounds__(128) void k_dequant(
    const int* __restrict__ q, const float* __restrict__ sc,
    bf16* __restrict__ w, int IN) {
    const int row = blockIdx.y;
    const int k = (blockIdx.x * 128 + threadIdx.x) * 8;
    if (k >= IN) return;
    const float s = sc[(size_t)row * (IN >> 5) + (k >> 5)];
    const size_t base = (size_t)row * IN + k;
    const int4 q0 = *(const int4*)(q + base);
    const int4 q1 = *(const int4*)(q + base + 4);
    bf16x8 o;
    o[0] = (bf16)(q0.x * s); o[1] = (bf16)(q0.y * s);
    o[2] = (bf16)(q0.z * s); o[3] = (bf16)(q0.w * s);
    o[4] = (bf16)(q1.x * s); o[5] = (bf16)(q1.y * s);
    o[6] = (bf16)(q1.z * s); o[7] = (bf16)(q1.w * s);
    *(bf16x8*)(w + base) = o;
}

// ---------------- Pass 1b: x f32 -> bf16 -----------------------------------
__global__ __launch_bounds__(256) void k_cvt(
    const float* __restrict__ x, bf16* __restrict__ xb, long long n8) {
    long long i = (long long)blockIdx.x * 256 + threadIdx.x;
    const long long stride = (long long)gridDim.x * 256;
    for (; i < n8; i += stride) {
        const float4 a = *(const float4*)(x + i * 8);
        const float4 b = *(const float4*)(x + i * 8 + 4);
        bf16x8 o;
        o[0] = (bf16)a.x; o[1] = (bf16)a.y; o[2] = (bf16)a.z; o[3] = (bf16)a.w;
        o[4] = (bf16)b.x; o[5] = (bf16)b.y; o[6] = (bf16)b.z; o[7] = (bf16)b.w;
        *(bf16x8*)(xb + i * 8) = o;
    }
}

// ---------------- Pass 2: bf16 GEMM, C = A @ B^T + bias --------------------
// A: [M][K] bf16 row-major (x), B: [N][K] bf16 row-major (W'), C: [M][N] f32.
// 128x128 tile, BK=32, 256 threads = 4 waves in 2x2, each wave 64x64 out
// via 4x4 frags of mfma_f32_16x16x32_bf16.
__global__ __launch_bounds__(256, 3) void k_gemm(
    const bf16* __restrict__ A, const bf16* __restrict__ B,
    const float* __restrict__ bias, float* __restrict__ C,
    int M, int N, int K) {
    __shared__ __align__(16) char sA[128 * 32 * 2];  // 8KB
    __shared__ __align__(16) char sB[128 * 32 * 2];  // 8KB
    const int tid = threadIdx.x;
    const int wv = tid >> 6;
    const int ln = tid & 63;
    const int nbn = N >> 7;
    // bijective XCD swizzle (m204 form; works for any nwg)
    const int nwg = gridDim.x;
    const int q8 = nwg >> 3, r8 = nwg & 7;
    const int xcd = blockIdx.x & 7, lin = blockIdx.x >> 3;
    const int swz = (xcd < r8 ? xcd * (q8 + 1)
                              : r8 * (q8 + 1) + (xcd - r8) * q8) + lin;
    const int bm = swz / nbn, bn = swz % nbn;
    const int wr = (wv >> 1) << 6;  // wave row offset in tile
    const int wc = (wv & 1) << 6;   // wave col offset in tile

    f32x4 acc[4][4] = {};

    const int rowstride = K << 1;  // bytes per row
    const char* Ab = (const char*)A + (size_t)(bm << 7) * rowstride;
    const char* Bb = (const char*)B + (size_t)(bn << 7) * rowstride;
    // staging: tile = 128 rows x 64B; 2 issues x (256 lanes x 16B)
    const int o0 = wv * 1024 + ln * 16;
    const int o1 = o0 + 4096;
    const int r0 = o0 >> 6, c0 = o0 & 63;
    const int r1 = o1 >> 6, c1 = o1 & 63;

    for (int kt = 0; kt < K; kt += 32) {
        __syncthreads();  // previous iter's LDS reads done
        const int kb = kt << 1;  // byte offset along K
        gload_lds16(Ab + (size_t)r0 * rowstride + kb + c0, sA + wv * 1024);
        gload_lds16(Ab + (size_t)r1 * rowstride + kb + c1, sA + 4096 + wv * 1024);
        gload_lds16(Bb + (size_t)r0 * rowstride + kb + c0, sB + wv * 1024);
        gload_lds16(Bb + (size_t)r1 * rowstride + kb + c1, sB + 4096 + wv * 1024);
        __syncthreads();  // waitcnt vmcnt(0) drained by compiler before barrier

        bf16x8 af[4], bg[4];
#pragma unroll
        for (int m = 0; m < 4; ++m)
            af[m] = *(const bf16x8*)(sA + ((wr + (m << 4) + (ln & 15)) << 6) +
                                     ((ln >> 4) << 4));
#pragma unroll
        for (int n = 0; n < 4; ++n)
            bg[n] = *(const bf16x8*)(sB + ((wc + (n << 4) + (ln & 15)) << 6) +
                                     ((ln >> 4) << 4));
#pragma unroll
        for (int m = 0; m < 4; ++m)
#pragma unroll
            for (int n = 0; n < 4; ++n)
                acc[m][n] = __builtin_amdgcn_mfma_f32_16x16x32_bf16(
                    af[m], bg[n], acc[m][n], 0, 0, 0);
    }

    // epilogue: D layout col=lane&15, row=(lane>>4)*4+reg (m89/m91-verified)
    float bv[4];
#pragma unroll
    for (int n = 0; n < 4; ++n)
        bv[n] = bias[(bn << 7) + wc + (n << 4) + (ln & 15)];
#pragma unroll
    for (int m = 0; m < 4; ++m) {
        const int grow0 = (bm << 7) + wr + (m << 4) + ((ln >> 4) << 2);
#pragma unroll
        for (int r = 0; r < 4; ++r) {
            float* Crow = C + (size_t)(grow0 + r) * N;
#pragma unroll
            for (int n = 0; n < 4; ++n)
                Crow[(bn << 7) + wc + (n << 4) + (ln & 15)] =
                    acc[m][n][r] + bv[n];
        }
    }
}

// ---------------- Fallback: fused dequant+GEMM (no workspace) --------------
__global__ __launch_bounds__(256) void k_fused(
    const float* __restrict__ X, const int* __restrict__ Q,
    const float* __restrict__ SC, const float* __restrict__ bias,
    float* __restrict__ C, int M, int N, int K) {
    __shared__ __align__(16) bf16 sA[128 * 32];
    __shared__ __align__(16) bf16 sB[128 * 32];
    const int tid = threadIdx.x;
    const int wv = tid >> 6;
    const int ln = tid & 63;
    const int nbn = N >> 7;
    const int nwg = gridDim.x;
    const int q8 = nwg >> 3, r8 = nwg & 7;
    const int xcd = blockIdx.x & 7, lin = blockIdx.x >> 3;
    const int swz = (xcd < r8 ? xcd * (q8 + 1)
                              : r8 * (q8 + 1) + (xcd - r8) * q8) + lin;
    const int bm = swz / nbn, bn = swz % nbn;
    const int wr = (wv >> 1) << 6;
    const int wc = (wv & 1) << 6;
    const int srow = tid >> 1;          // staging row 0..127
    const int sk = (tid & 1) << 4;      // staging k offset 0/16

    f32x4 acc[4][4] = {};
    const float* xrow = X + (size_t)((bm << 7) + srow) * K + sk;
    const int* qrow = Q + (size_t)((bn << 7) + srow) * K + sk;
    const float* scrow = SC + (size_t)((bn << 7) + srow) * (K >> 5);

    for (int kt = 0; kt < K; kt += 32) {
        const float4 a0 = *(const float4*)(xrow + kt);
        const float4 a1 = *(const float4*)(xrow + kt + 4);
        const float4 a2 = *(const float4*)(xrow + kt + 8);
        const float4 a3 = *(const float4*)(xrow + kt + 12);
        const int4 q0 = *(const int4*)(qrow + kt);
        const int4 q1 = *(const int4*)(qrow + kt + 4);
        const int4 q2 = *(const int4*)(qrow + kt + 8);
        const int4 q3 = *(const int4*)(qrow + kt + 12);
        const float s = scrow[(kt + sk) >> 5];
        bf16x8 wa0, wa1, wb0, wb1;
        wa0[0] = (bf16)a0.x; wa0[1] = (bf16)a0.y; wa0[2] = (bf16)a0.z; wa0[3] = (bf16)a0.w;
        wa0[4] = (bf16)a1.x; wa0[5] = (bf16)a1.y; wa0[6] = (bf16)a1.z; wa0[7] = (bf16)a1.w;
        wa1[0] = (bf16)a2.x; wa1[1] = (bf16)a2.y; wa1[2] = (bf16)a2.z; wa1[3] = (bf16)a2.w;
        wa1[4] = (bf16)a3.x; wa1[5] = (bf16)a3.y; wa1[6] = (bf16)a3.z; wa1[7] = (bf16)a3.w;
        wb0[0] = (bf16)(q0.x * s); wb0[1] = (bf16)(q0.y * s);
        wb0[2] = (bf16)(q0.z * s); wb0[3] = (bf16)(q0.w * s);
        wb0[4] = (bf16)(q1.x * s); wb0[5] = (bf16)(q1.y * s);
        wb0[6] = (bf16)(q1.z * s); wb0[7] = (bf16)(q1.w * s);
        wb1[0] = (bf16)(q2.x * s); wb1[1] = (bf16)(q2.y * s);
        wb1[2] = (bf16)(q2.z * s); wb1[3] = (bf16)(q2.w * s);
        wb1[4] = (bf16)(q3.x * s); wb1[5] = (bf16)(q3.y * s);
        wb1[6] = (bf16)(q3.z * s); wb1[7] = (bf16)(q3.w * s);
        __syncthreads();  // previous iter's LDS reads done
        *(bf16x8*)(sA + srow * 32 + sk) = wa0;
        *(bf16x8*)(sA + srow * 32 + sk + 8) = wa1;
        *(bf16x8*)(sB + srow * 32 + sk) = wb0;
        *(bf16x8*)(sB + srow * 32 + sk + 8) = wb1;
        __syncthreads();

        bf16x8 af[4], bg[4];
#pragma unroll
        for (int m = 0; m < 4; ++m)
            af[m] = *(const bf16x8*)(sA + ((wr + (m << 4) + (ln & 15)) << 5) +
                                     ((ln >> 4) << 3));
#pragma unroll
        for (int n = 0; n < 4; ++n)
            bg[n] = *(const bf16x8*)(sB + ((wc + (n << 4) + (ln & 15)) << 5) +
                                     ((ln >> 4) << 3));
#pragma unroll
        for (int m = 0; m < 4; ++m)
#pragma unroll
            for (int n = 0; n < 4; ++n)
                acc[m][n] = __builtin_amdgcn_mfma_f32_16x16x32_bf16(
                    af[m], bg[n], acc[m][n], 0, 0, 0);
    }

    float bv[4];
#pragma unroll
    for (int n = 0; n < 4; ++n)
        bv[n] = bias[(bn << 7) + wc + (n << 4) + (ln & 15)];
#pragma unroll
    for (int m = 0; m < 4; ++m) {
        const int grow0 = (bm << 7) + wr + (m << 4) + ((ln >> 4) << 2);
#pragma unroll
        for (int r = 0; r < 4; ++r) {
            float* Crow = C + (size_t)(grow0 + r) * N;
#pragma unroll
            for (int n = 0; n < 4; ++n)
                Crow[(bn << 7) + wc + (n << 4) + (ln & 15)] =
                    acc[m][n][r] + bv[n];
        }
    }
}

extern "C" void kernel_launch(void* const* d_in, const int* in_sizes, int n_in,
                              void* d_out, int out_size, void* d_ws, size_t ws_size,
                              hipStream_t stream) {
    const float* x = (const float*)d_in[0];
    const int* wq = (const int*)d_in[1];
    const float* sc = (const float*)d_in[2];
    const float* bias = (const float*)d_in[3];
    float* out = (float*)d_out;

    const long long xN = in_sizes[0];            // TOK*IN
    const long long wN = in_sizes[1];            // OUT*IN
    const int OUT = in_sizes[3];                 // bias length
    const int IN = (int)(wN / OUT);
    const int TOK = (int)(xN / IN);
    const int M = TOK, N = OUT, K = IN;

    const size_t wb_bytes = (size_t)wN * 2;      // bf16 W'
    const size_t xb_bytes = (size_t)xN * 2;      // bf16 x
    const int grid = (M / 128) * (N / 128);

    if (ws_size >= wb_bytes + xb_bytes) {
        bf16* Wb = (bf16*)d_ws;
        bf16* Xb = (bf16*)((char*)d_ws + wb_bytes);
        dim3 dq_grid((IN / 8 + 127) / 128, OUT);
        k_dequant<<<dq_grid, 128, 0, stream>>>(wq, sc, Wb, IN);
        const long long n8 = xN / 8;
        int cvt_blocks = (int)((n8 + 255) / 256);
        if (cvt_blocks > 2048) cvt_blocks = 2048;
        k_cvt<<<cvt_blocks, 256, 0, stream>>>(x, Xb, n8);
        k_gemm<<<grid, 256, 0, stream>>>(Xb, Wb, bias, out, M, N, K);
    } else {
        k_fused<<<grid, 256, 0, stream>>>(x, wq, sc, bias, out, M, N, K);
    }
}

// Round 2
// 338.548 us; speedup vs baseline: 1.4550x; 1.4550x over previous
//
#include <hip/hip_runtime.h>
#include <hip/hip_bf16.h>
#include <stdint.h>

// DequantingLinear: out[TOK,OUT] = x[TOK,IN] @ dequant(w_q,w_scales)^T + bias
// TOK=4096, IN=3072, OUT=12288, QK=32.
// R2: 256x256-tile BK=64 8-wave GEMM with counted-vmcnt pipeline (T4),
// XOR-swizzled LDS (T2), setprio (T5). Dequant/cvt passes unchanged.

typedef __bf16 bf16;
typedef __bf16 bf16x8 __attribute__((ext_vector_type(8)));
typedef float f32x4 __attribute__((ext_vector_type(4)));

#define AS1 __attribute__((address_space(1)))
#define AS3 __attribute__((address_space(3)))

__device__ __forceinline__ void gload_lds16(const void* g, void* l) {
    // 16B/lane; LDS dest = wave-uniform base + lane*16 (hardware rule)
    __builtin_amdgcn_global_load_lds((AS1 void*)g, (AS3 void*)l, 16, 0, 0);
}

#define MFMA16(d, x, y) d = __builtin_amdgcn_mfma_f32_16x16x32_bf16(x, y, d, 0, 0, 0)

// ---------------- Pass 1a: dequantize w_q (int32) * scale -> bf16 ----------
__global__ __launch_bounds__(128) void k_dequant(
    const int* __restrict__ q, const float* __restrict__ sc,
    bf16* __restrict__ w, int IN) {
    const int row = blockIdx.y;
    const int k = (blockIdx.x * 128 + threadIdx.x) * 8;
    if (k >= IN) return;
    const float s = sc[(size_t)row * (IN >> 5) + (k >> 5)];
    const size_t base = (size_t)row * IN + k;
    const int4 q0 = *(const int4*)(q + base);
    const int4 q1 = *(const int4*)(q + base + 4);
    bf16x8 o;
    o[0] = (bf16)(q0.x * s); o[1] = (bf16)(q0.y * s);
    o[2] = (bf16)(q0.z * s); o[3] = (bf16)(q0.w * s);
    o[4] = (bf16)(q1.x * s); o[5] = (bf16)(q1.y * s);
    o[6] = (bf16)(q1.z * s); o[7] = (bf16)(q1.w * s);
    *(bf16x8*)(w + base) = o;
}

// ---------------- Pass 1b: x f32 -> bf16 -----------------------------------
__global__ __launch_bounds__(256) void k_cvt(
    const float* __restrict__ x, bf16* __restrict__ xb, long long n8) {
    long long i = (long long)blockIdx.x * 256 + threadIdx.x;
    const long long stride = (long long)gridDim.x * 256;
    for (; i < n8; i += stride) {
        const float4 a = *(const float4*)(x + i * 8);
        const float4 b = *(const float4*)(x + i * 8 + 4);
        bf16x8 o;
        o[0] = (bf16)a.x; o[1] = (bf16)a.y; o[2] = (bf16)a.z; o[3] = (bf16)a.w;
        o[4] = (bf16)b.x; o[5] = (bf16)b.y; o[6] = (bf16)b.z; o[7] = (bf16)b.w;
        *(bf16x8*)(xb + i * 8) = o;
    }
}

// ---------------- Pass 2: 256x256 bf16 GEMM, C = A @ B^T + bias ------------
// A:[M][K] bf16 (x), B:[N][K] bf16 (W'), C:[M][N] f32.
// 512 thr = 8 waves (2M x 4N); wave out = 128x64 (8x4 frags, 16x16x32 MFMA).
// LDS: 2 bufs x (A 32KB + B 32KB) = 128KB. Swizzle: byte col ^= (row&7)<<4,
// pre-applied on global source (linear global_load_lds dest) + on ds_read.
// Pipeline: tile t+1 always in flight across the end-of-tile vmcnt(8);
// tile t+2 issued into buf[t&1] after an lgkm-drained barrier (safe overwrite).
__global__ __launch_bounds__(512, 2) void k_gemm256(
    const bf16* __restrict__ A, const bf16* __restrict__ B,
    const float* __restrict__ bias, float* __restrict__ C,
    int M, int N, int K) {
    __shared__ __align__(16) char lds[131072];
    const int tid = threadIdx.x;
    const int wv = tid >> 6, ln = tid & 63;
    const int wm = wv >> 2, wn = wv & 3;  // 2 x 4 wave grid
    const int nbn = N >> 8;
    // bijective XCD swizzle (m204)
    const int nwg = gridDim.x;
    const int q8 = nwg >> 3, r8 = nwg & 7;
    const int xcd = blockIdx.x & 7, lin = blockIdx.x >> 3;
    const int swz = (xcd < r8 ? xcd * (q8 + 1)
                              : r8 * (q8 + 1) + (xcd - r8) * q8) + lin;
    const int bm = swz / nbn, bn = swz % nbn;

    // ---- staging addressing (pre-swizzled global source, linear LDS dest)
    // LDS byte o = j*8192 + tid*16  ->  row = j*64 + (tid>>3),
    // logical colbyte = ((tid&7) ^ ((tid>>3)&7)) * 16
    const size_t rowb = (size_t)K * 2;
    const int srow = tid >> 3;
    const int scol = (((tid ^ (tid >> 3)) & 7) << 4);
    const char* Ag = (const char*)A + ((size_t)(bm << 8) + srow) * rowb + scol;
    const char* Bg = (const char*)B + ((size_t)(bn << 8) + srow) * rowb + scol;
    const int ldsw = wv << 10;  // wave-uniform LDS sub-base

#define STAGE(cb_, kt_) do {                                                  \
        const size_t kb_ = (size_t)(kt_) << 1;                                \
        _Pragma("unroll")                                                     \
        for (int j = 0; j < 4; ++j)                                           \
            gload_lds16(Ag + (size_t)(j << 6) * rowb + kb_,                   \
                        lds + (cb_) + (j << 13) + ldsw);                      \
        _Pragma("unroll")                                                     \
        for (int j = 0; j < 4; ++j)                                           \
            gload_lds16(Bg + (size_t)(j << 6) * rowb + kb_,                   \
                        lds + (cb_) + 32768 + (j << 13) + ldsw);              \
    } while (0)

    // ---- ds_read fragment addressing (swizzled)
    // logical col = kk*64 + (ln>>4)*16; swizzled = col ^ ((row&7)<<4), row&7==ln&7
    // bit6 = kk ^ ((ln>>2)&1), bits5:4 = (ln>>4) ^ (ln&3)
    const int colx = ((ln & 4) << 4) | ((((ln >> 4) ^ ln) & 3) << 4);
    const int c0 = colx, c1 = colx ^ 64;
    const int abase = (((wm << 7) + (ln & 15)) << 7);  // row*128
    const int bbase = (((wn << 6) + (ln & 15)) << 7);

    const int NT = K >> 6;
    f32x4 acc[8][4] = {};

    // ---- prologue: tiles 0,1 in flight; wait tile 0 only (vmcnt(8))
    STAGE(0, 0);
    if (NT > 1) {
        STAGE(65536, 64);
        asm volatile("s_waitcnt vmcnt(8)" ::: "memory");
    } else {
        asm volatile("s_waitcnt vmcnt(0)" ::: "memory");
    }
    __builtin_amdgcn_sched_barrier(0);
    __builtin_amdgcn_s_barrier();
    __builtin_amdgcn_sched_barrier(0);

#pragma unroll 2
    for (int t = 0; t < NT; ++t) {
        const int cb = (t & 1) << 16;
        const char* bA = lds + cb;
        const char* bB = lds + cb + 32768;
        bf16x8 a[8], b[8];
#pragma unroll
        for (int n = 0; n < 4; ++n) {
            b[n * 2 + 0] = *(const bf16x8*)(bB + bbase + (n << 11) + c0);
            b[n * 2 + 1] = *(const bf16x8*)(bB + bbase + (n << 11) + c1);
        }
#pragma unroll
        for (int m = 0; m < 4; ++m) {
            a[m * 2 + 0] = *(const bf16x8*)(bA + abase + (m << 11) + c0);
            a[m * 2 + 1] = *(const bf16x8*)(bA + abase + (m << 11) + c1);
        }
        __builtin_amdgcn_s_setprio(1);
#pragma unroll
        for (int m = 0; m < 4; ++m)
#pragma unroll
            for (int n = 0; n < 4; ++n) {
                MFMA16(acc[m][n], a[m * 2 + 0], b[n * 2 + 0]);
                MFMA16(acc[m][n], a[m * 2 + 1], b[n * 2 + 1]);
            }
        __builtin_amdgcn_s_setprio(0);
        // second row-half of this wave's A
#pragma unroll
        for (int m = 0; m < 4; ++m) {
            a[m * 2 + 0] = *(const bf16x8*)(bA + abase + 8192 + (m << 11) + c0);
            a[m * 2 + 1] = *(const bf16x8*)(bA + abase + 8192 + (m << 11) + c1);
        }
        // all ds_reads of buf[cb] done -> safe to overwrite with tile t+2
        asm volatile("s_waitcnt lgkmcnt(0)" ::: "memory");
        __builtin_amdgcn_sched_barrier(0);
        __builtin_amdgcn_s_barrier();
        __builtin_amdgcn_sched_barrier(0);
        if (t + 2 < NT) STAGE(cb, (t + 2) << 6);
        __builtin_amdgcn_s_setprio(1);
#pragma unroll
        for (int m = 0; m < 4; ++m)
#pragma unroll
            for (int n = 0; n < 4; ++n) {
                MFMA16(acc[m + 4][n], a[m * 2 + 0], b[n * 2 + 0]);
                MFMA16(acc[m + 4][n], a[m * 2 + 1], b[n * 2 + 1]);
            }
        __builtin_amdgcn_s_setprio(0);
        // tile t+1 must be resident for next iter; tile t+2 (8 newest) stays in flight
        if (t + 2 < NT)
            asm volatile("s_waitcnt vmcnt(8)" ::: "memory");
        else if (t + 1 < NT)
            asm volatile("s_waitcnt vmcnt(0)" ::: "memory");
        __builtin_amdgcn_sched_barrier(0);
        __builtin_amdgcn_s_barrier();
        __builtin_amdgcn_sched_barrier(0);
    }
#undef STAGE

    // ---- epilogue: D layout col=lane&15, row=(lane>>4)*4+reg
    const int erow = (bm << 8) + (wm << 7) + ((ln >> 4) << 2);
    const int ecol = (bn << 8) + (wn << 6) + (ln & 15);
    float bv[4];
#pragma unroll
    for (int n = 0; n < 4; ++n) bv[n] = bias[ecol + (n << 4)];
#pragma unroll
    for (int m = 0; m < 8; ++m)
#pragma unroll
        for (int r = 0; r < 4; ++r) {
            float* Crow = C + (size_t)(erow + (m << 4) + r) * N + ecol;
#pragma unroll
            for (int n = 0; n < 4; ++n)
                Crow[n << 4] = acc[m][n][r] + bv[n];
        }
}

// ---------------- Fallback: fused dequant+GEMM (no workspace) --------------
__global__ __launch_bounds__(256) void k_fused(
    const float* __restrict__ X, const int* __restrict__ Q,
    const float* __restrict__ SC, const float* __restrict__ bias,
    float* __restrict__ C, int M, int N, int K) {
    __shared__ __align__(16) bf16 sA[128 * 32];
    __shared__ __align__(16) bf16 sB[128 * 32];
    const int tid = threadIdx.x;
    const int wv = tid >> 6;
    const int ln = tid & 63;
    const int nbn = N >> 7;
    const int nwg = gridDim.x;
    const int q8 = nwg >> 3, r8 = nwg & 7;
    const int xcd = blockIdx.x & 7, lin = blockIdx.x >> 3;
    const int swz = (xcd < r8 ? xcd * (q8 + 1)
                              : r8 * (q8 + 1) + (xcd - r8) * q8) + lin;
    const int bm = swz / nbn, bn = swz % nbn;
    const int wr = (wv >> 1) << 6;
    const int wc = (wv & 1) << 6;
    const int srow = tid >> 1;
    const int sk = (tid & 1) << 4;

    f32x4 acc[4][4] = {};
    const float* xrow = X + (size_t)((bm << 7) + srow) * K + sk;
    const int* qrow = Q + (size_t)((bn << 7) + srow) * K + sk;
    const float* scrow = SC + (size_t)((bn << 7) + srow) * (K >> 5);

    for (int kt = 0; kt < K; kt += 32) {
        const float4 a0 = *(const float4*)(xrow + kt);
        const float4 a1 = *(const float4*)(xrow + kt + 4);
        const float4 a2 = *(const float4*)(xrow + kt + 8);
        const float4 a3 = *(const float4*)(xrow + kt + 12);
        const int4 q0 = *(const int4*)(qrow + kt);
        const int4 q1 = *(const int4*)(qrow + kt + 4);
        const int4 q2 = *(const int4*)(qrow + kt + 8);
        const int4 q3 = *(const int4*)(qrow + kt + 12);
        const float s = scrow[(kt + sk) >> 5];
        bf16x8 wa0, wa1, wb0, wb1;
        wa0[0] = (bf16)a0.x; wa0[1] = (bf16)a0.y; wa0[2] = (bf16)a0.z; wa0[3] = (bf16)a0.w;
        wa0[4] = (bf16)a1.x; wa0[5] = (bf16)a1.y; wa0[6] = (bf16)a1.z; wa0[7] = (bf16)a1.w;
        wa1[0] = (bf16)a2.x; wa1[1] = (bf16)a2.y; wa1[2] = (bf16)a2.z; wa1[3] = (bf16)a2.w;
        wa1[4] = (bf16)a3.x; wa1[5] = (bf16)a3.y; wa1[6] = (bf16)a3.z; wa1[7] = (bf16)a3.w;
        wb0[0] = (bf16)(q0.x * s); wb0[1] = (bf16)(q0.y * s);
        wb0[2] = (bf16)(q0.z * s); wb0[3] = (bf16)(q0.w * s);
        wb0[4] = (bf16)(q1.x * s); wb0[5] = (bf16)(q1.y * s);
        wb0[6] = (bf16)(q1.z * s); wb0[7] = (bf16)(q1.w * s);
        wb1[0] = (bf16)(q2.x * s); wb1[1] = (bf16)(q2.y * s);
        wb1[2] = (bf16)(q2.z * s); wb1[3] = (bf16)(q2.w * s);
        wb1[4] = (bf16)(q3.x * s); wb1[5] = (bf16)(q3.y * s);
        wb1[6] = (bf16)(q3.z * s); wb1[7] = (bf16)(q3.w * s);
        __syncthreads();
        *(bf16x8*)(sA + srow * 32 + sk) = wa0;
        *(bf16x8*)(sA + srow * 32 + sk + 8) = wa1;
        *(bf16x8*)(sB + srow * 32 + sk) = wb0;
        *(bf16x8*)(sB + srow * 32 + sk + 8) = wb1;
        __syncthreads();

        bf16x8 af[4], bg[4];
#pragma unroll
        for (int m = 0; m < 4; ++m)
            af[m] = *(const bf16x8*)(sA + ((wr + (m << 4) + (ln & 15)) << 5) +
                                     ((ln >> 4) << 3));
#pragma unroll
        for (int n = 0; n < 4; ++n)
            bg[n] = *(const bf16x8*)(sB + ((wc + (n << 4) + (ln & 15)) << 5) +
                                     ((ln >> 4) << 3));
#pragma unroll
        for (int m = 0; m < 4; ++m)
#pragma unroll
            for (int n = 0; n < 4; ++n)
                acc[m][n] = __builtin_amdgcn_mfma_f32_16x16x32_bf16(
                    af[m], bg[n], acc[m][n], 0, 0, 0);
    }

    float bv[4];
#pragma unroll
    for (int n = 0; n < 4; ++n)
        bv[n] = bias[(bn << 7) + wc + (n << 4) + (ln & 15)];
#pragma unroll
    for (int m = 0; m < 4; ++m) {
        const int grow0 = (bm << 7) + wr + (m << 4) + ((ln >> 4) << 2);
#pragma unroll
        for (int r = 0; r < 4; ++r) {
            float* Crow = C + (size_t)(grow0 + r) * N;
#pragma unroll
            for (int n = 0; n < 4; ++n)
                Crow[(bn << 7) + wc + (n << 4) + (ln & 15)] =
                    acc[m][n][r] + bv[n];
        }
    }
}

extern "C" void kernel_launch(void* const* d_in, const int* in_sizes, int n_in,
                              void* d_out, int out_size, void* d_ws, size_t ws_size,
                              hipStream_t stream) {
    const float* x = (const float*)d_in[0];
    const int* wq = (const int*)d_in[1];
    const float* sc = (const float*)d_in[2];
    const float* bias = (const float*)d_in[3];
    float* out = (float*)d_out;

    const long long xN = in_sizes[0];  // TOK*IN
    const long long wN = in_sizes[1];  // OUT*IN
    const int OUT = in_sizes[3];       // bias length
    const int IN = (int)(wN / OUT);
    const int TOK = (int)(xN / IN);
    const int M = TOK, N = OUT, K = IN;

    const size_t wb_bytes = (size_t)wN * 2;
    const size_t xb_bytes = (size_t)xN * 2;
    const bool tiles256 = (M % 256 == 0) && (N % 256 == 0) && (K % 64 == 0);

    if (tiles256 && ws_size >= wb_bytes + xb_bytes) {
        bf16* Wb = (bf16*)d_ws;
        bf16* Xb = (bf16*)((char*)d_ws + wb_bytes);
        dim3 dq_grid((IN / 8 + 127) / 128, OUT);
        k_dequant<<<dq_grid, 128, 0, stream>>>(wq, sc, Wb, IN);
        const long long n8 = xN / 8;
        int cvt_blocks = (int)((n8 + 255) / 256);
        if (cvt_blocks > 2048) cvt_blocks = 2048;
        k_cvt<<<cvt_blocks, 256, 0, stream>>>(x, Xb, n8);
        const int grid = (M / 256) * (N / 256);
        k_gemm256<<<grid, 512, 0, stream>>>(Xb, Wb, bias, out, M, N, K);
    } else {
        const int grid = (M / 128) * (N / 128);
        k_fused<<<grid, 256, 0, stream>>>(x, wq, sc, bias, out, M, N, K);
    }
}